// Round 5
// baseline (5102.788 us; speedup 1.0000x reference)
//
#include <hip/hip_runtime.h>
#include <cstddef>

#define F_IN_RELU    1
#define F_OUT_RELU   2
#define F_RESIDUAL   4
#define F_COMB4      8
#define F_SPLIT      16
#define F_IN_BNORM   32
#define F_STATS      64

typedef __attribute__((ext_vector_type(8))) short short8;
typedef __attribute__((ext_vector_type(4))) short short4v;
typedef __attribute__((ext_vector_type(4))) float floatx4;

__device__ inline float bf2f(short h) {
  union { unsigned int u; float f; } v;
  v.u = ((unsigned int)(unsigned short)h) << 16;
  return v.f;
}
__device__ inline short f2bf(float f) {
  union { float f; unsigned int u; } v; v.f = f;
  unsigned int r = v.u + 0x7fffu + ((v.u >> 16) & 1u);
  return (short)(r >> 16);
}

// ---------------- init: zero bn sums + loss accumulators ----------------
__global__ void k_init(float* p) {
  for (int i = threadIdx.x; i < 1664; i += 256) p[i] = 0.f;
}

// ---------------- weight swizzles ----------------
// fp32 w[Cout][Cin][K][K] -> bf16 wq[co_grp16][kk][ci_chunk32][lane64][8]
__global__ __launch_bounds__(256) void k_wswz(
    const float* __restrict__ w, short* __restrict__ wq,
    int Cin, int K2, int per_layer)
{
  int idx = blockIdx.x * 256 + threadIdx.x;
  if (idx >= per_layer) return;
  int layer = blockIdx.y;
  w  += (size_t)layer * per_layer;
  wq += (size_t)layer * per_layer;
  int nch = Cin >> 5;
  int j = idx & 7;
  int lane = (idx >> 3) & 63;
  int r = idx >> 9;
  int cich = r % nch; int r2 = r / nch;
  int kk = r2 % K2;   int co_grp = r2 / K2;
  int co = co_grp * 16 + (lane & 15);
  int ci = (cich << 5) + ((lane >> 4) << 3) + j;
  wq[idx] = f2bf(w[((size_t)co * Cin + ci) * K2 + kk]);
}

// conv0 weights -> A-frag layout with K padded 48->64
__global__ __launch_bounds__(256) void k_wswz0m(
    const float* __restrict__ w, short* __restrict__ wq)
{
  int idx = blockIdx.x * 256 + threadIdx.x;
  if (idx >= 16384) return;
  int co = idx >> 6, k = idx & 63;
  float val = (k < 48) ? w[co * 48 + k] : 0.f;
  int cich = k >> 5;
  int lane = (((k >> 3) & 3) << 4) | (co & 15);
  int j = k & 7;
  int cg = co >> 4;
  wq[((size_t)(cg * 2 + cich) * 64 + lane) * 8 + j] = f2bf(val);
}

// im2col for conv0: out[px][64] bf16, k = ci*16+ky*4+kx, padded with zeros
__global__ __launch_bounds__(256) void k_im2col(
    const float* __restrict__ x, short* __restrict__ out)
{
  int idx = blockIdx.x * 256 + threadIdx.x;
  int k = idx & 63;
  int px = idx >> 6;
  int b = px >> 12;
  int rem = px & 4095;
  int y = rem >> 6, xc = rem & 63;
  int ci = k >> 4, t = k & 15;
  int ky = t >> 2, kx = t & 3;
  float v = 0.f;
  if (ci < 3) {
    int iy = 2 * y - 1 + ky, ix = 2 * xc - 1 + kx;
    if ((unsigned)iy < 128u && (unsigned)ix < 128u)
      v = x[((b * 3 + ci) * 128 + iy) * 128 + ix];
  }
  out[idx] = f2bf(v);
}

// deconv weights: w[ci][o][kk(16)] -> bf16 wdt[kk][o][ci]
__global__ __launch_bounds__(256) void k_wswz_dd(
    const float* __restrict__ w, short* __restrict__ wdt)
{
  int idx = blockIdx.x * 256 + threadIdx.x;
  if (idx >= 12288) return;
  int ci = idx & 255, t = idx >> 8;
  int o = t % 3, kk = t / 3;
  wdt[idx] = f2bf(w[(ci * 3 + o) * 16 + kk]);
}

// codebook norms |c|^2
__global__ __launch_bounds__(256) void k_ccn(
    const float* __restrict__ cb, float* __restrict__ cc)
{
  int code = blockIdx.x * 256 + threadIdx.x;
  const float4* r = (const float4*)(cb + (size_t)code * 256);
  float s = 0.f;
  for (int i = 0; i < 64; ++i) {
    float4 v = r[i];
    s += v.x * v.x + v.y * v.y + v.z * v.z + v.w * v.w;
  }
  cc[code] = s;
}

// finalize BN: scale/shift from sums
__global__ __launch_bounds__(512) void k_bnfin(
    const float* __restrict__ sums, const float* __restrict__ g,
    const float* __restrict__ beta, float* __restrict__ ss, int C)
{
  int c = threadIdx.x;
  if (c >= C) return;
  float m = sums[c] * (1.f / 32768.f);
  float var = sums[C + c] * (1.f / 32768.f) - m * m;
  float sc = g[c] * rsqrtf(var + 1e-5f);
  ss[c] = sc;
  ss[C + c] = beta[c] - m * sc;
}

// ---------------- MFMA implicit-GEMM conv, NHWC bf16 ----------------
// Block: 256 thr = 4 waves = (2 rows) x (2 co-halves); wave tile 64co x 64px.
// Grid: (Cout/128 or K-split4, 32 y-pairs, 8 b).
template <int K>
__global__ __launch_bounds__(256) void k_mconv(
    const short* __restrict__ in, short* __restrict__ out,
    short* __restrict__ outf,
    const short* __restrict__ scr4,
    const float* __restrict__ bias_t,
    const float* __restrict__ ss_in, float* __restrict__ sums_out,
    const short* __restrict__ wq, const float* __restrict__ bias,
    int Cin, int c0, int c1, int Cout, int flags)
{
  constexpr int K2 = K * K;
  constexpr int XS = 40;                 // padded x stride (ushorts)
  constexpr int NR = (K == 3) ? 4 : 1;
  constexpr int NX = (K == 3) ? 66 : 128;
  __shared__ __align__(16) short s_in[NR * NX * XS];
  __shared__ float btl[128];
  __shared__ float ssl[1024];

  int tid = threadIdx.x;
  int lane = tid & 63;
  int wave = tid >> 6;
  int m = lane & 15, quad = lane >> 4;
  int wr = wave >> 1, wc = wave & 1;
  int y2 = blockIdx.y * 2, b = blockIdx.z;
  int coblk = (flags & F_SPLIT) ? 0 : blockIdx.x;
  int nch = Cin >> 5;

  if ((flags & F_COMB4) && tid < 128) btl[tid] = bias_t[tid];
  if (flags & F_IN_BNORM) {
    for (int u = tid; u < 2 * Cin; u += 256) ssl[u] = ss_in[u];
  }

  int cc0 = c0, cc1 = c1;
  if (flags & F_SPLIT) {
    int quarter = nch >> 2;
    cc0 = blockIdx.x * quarter; cc1 = cc0 + quarter;
    outf += (size_t)blockIdx.x * 4194304;
  }

  floatx4 acc[4][4];
  #pragma unroll
  for (int f = 0; f < 4; ++f)
    #pragma unroll
    for (int p = 0; p < 4; ++p) acc[f][p] = (floatx4){0.f, 0.f, 0.f, 0.f};

  for (int cich = cc0; cich < cc1; ++cich) {
    __syncthreads();
    if (K == 3) {
      for (int u = tid; u < 4 * 66 * 4; u += 256) {
        int o = u & 3; int t2 = u >> 2;
        int xp = t2 % 66; int row = t2 / 66;
        int gy = y2 - 1 + row, gx = xp - 1;
        int ch = (cich << 5) + (o << 3);
        short8 v = {0, 0, 0, 0, 0, 0, 0, 0};
        if ((unsigned)gy < 64u && (unsigned)gx < 64u)
          v = *(const short8*)&in[((size_t)((b * 64 + gy) * 64 + gx)) * Cin + ch];
        if (flags & F_IN_BNORM) {
          #pragma unroll
          for (int i = 0; i < 8; ++i) {
            float f2 = bf2f(v[i]) * ssl[ch + i] + ssl[Cin + ch + i];
            v[i] = f2bf(f2 > 0.f ? f2 : 0.f);
          }
        } else if (flags & F_IN_RELU) {
          #pragma unroll
          for (int i = 0; i < 8; ++i) if (v[i] < 0) v[i] = 0;
        }
        *(short8*)&s_in[(row * 66 + xp) * XS + (o << 3)] = v;
      }
    } else {
      if (flags & F_COMB4) {
        for (int u = tid; u < 512; u += 256) {
          int o = u & 3; int xp = u >> 2;
          int ch = (cich << 5) + (o << 3);
          size_t base = ((size_t)((b * 64 + y2) * 64 + xp)) * 128 + ch;
          float va[8];
          #pragma unroll
          for (int i = 0; i < 8; ++i) va[i] = btl[ch + i];
          #pragma unroll
          for (int q = 0; q < 4; ++q) {
            short8 aq = *(const short8*)&scr4[(size_t)q * 4194304 + base];
            #pragma unroll
            for (int i = 0; i < 8; ++i) va[i] += bf2f(aq[i]);
          }
          short8 v;
          #pragma unroll
          for (int i = 0; i < 8; ++i) v[i] = f2bf(va[i] > 0.f ? va[i] : 0.f);
          *(short8*)&s_in[xp * XS + (o << 3)] = v;
        }
      } else {
        for (int u = tid; u < 512; u += 256) {
          int o = u & 3; int xp = u >> 2;
          short8 v = *(const short8*)&in[((size_t)((b * 64 + y2) * 64 + xp)) * Cin + (cich << 5) + (o << 3)];
          if (flags & F_IN_RELU) {
            #pragma unroll
            for (int i = 0; i < 8; ++i) if (v[i] < 0) v[i] = 0;
          }
          *(short8*)&s_in[xp * XS + (o << 3)] = v;
        }
      }
    }
    __syncthreads();

    #pragma unroll
    for (int kk = 0; kk < K2; ++kk) {
      int ky = (K == 3) ? (kk / 3) : 0;
      int kx = (K == 3) ? (kk - ky * 3) : 0;
      short8 af[4];
      #pragma unroll
      for (int f = 0; f < 4; ++f) {
        int cg = coblk * 8 + wc * 4 + f;
        af[f] = *(const short8*)&wq[(((size_t)(cg * K2 + kk) * nch + cich) * 64 + lane) * 8];
      }
      #pragma unroll
      for (int p = 0; p < 4; ++p) {
        short8 bv;
        if (K == 3)
          bv = *(const short8*)&s_in[((wr + ky) * 66 + p * 16 + m + kx) * XS + (quad << 3)];
        else
          bv = *(const short8*)&s_in[(wr * 64 + p * 16 + m) * XS + (quad << 3)];
        #pragma unroll
        for (int f = 0; f < 4; ++f)
          acc[f][p] = __builtin_amdgcn_mfma_f32_16x16x32_bf16(af[f], bv, acc[f][p], 0, 0, 0);
      }
    }
  }

  int pixrow = (b * 64 + y2 + wr) * 64;

  if (flags & F_SPLIT) {
    #pragma unroll
    for (int f = 0; f < 4; ++f) {
      int co_l = wc * 64 + f * 16 + quad * 4;
      #pragma unroll
      for (int p = 0; p < 4; ++p) {
        int x = p * 16 + m;
        short4v sv;
        #pragma unroll
        for (int r = 0; r < 4; ++r) sv[r] = f2bf(acc[f][p][r]);
        *(short4v*)&outf[(size_t)(pixrow + x) * 128 + co_l] = sv;
      }
    }
    return;
  }

  #pragma unroll
  for (int f = 0; f < 4; ++f) {
    int co4 = coblk * 128 + wc * 64 + f * 16 + quad * 4;
    floatx4 bv4 = *(const floatx4*)&bias[co4];
    float sv1[4] = {0.f, 0.f, 0.f, 0.f};
    float sv2[4] = {0.f, 0.f, 0.f, 0.f};
    #pragma unroll
    for (int p = 0; p < 4; ++p) {
      int x = p * 16 + m;
      size_t oidx = (size_t)(pixrow + x) * Cout + co4;
      float v[4];
      #pragma unroll
      for (int r = 0; r < 4; ++r) v[r] = acc[f][p][r] + bv4[r];
      if (flags & F_RESIDUAL) {
        short4v rr = *(const short4v*)&out[oidx];
        #pragma unroll
        for (int r = 0; r < 4; ++r) v[r] += bf2f(rr[r]);
      }
      if (flags & F_OUT_RELU) {
        #pragma unroll
        for (int r = 0; r < 4; ++r) v[r] = v[r] > 0.f ? v[r] : 0.f;
      }
      if (flags & F_STATS) {
        #pragma unroll
        for (int r = 0; r < 4; ++r) { sv1[r] += v[r]; sv2[r] += v[r] * v[r]; }
      }
      short4v sv;
      #pragma unroll
      for (int r = 0; r < 4; ++r) sv[r] = f2bf(v[r]);
      *(short4v*)&out[oidx] = sv;
    }
    if (flags & F_STATS) {
      #pragma unroll
      for (int r = 0; r < 4; ++r) {
        float a = sv1[r], a2 = sv2[r];
        #pragma unroll
        for (int off = 1; off <= 8; off <<= 1) {
          a += __shfl_xor(a, off);
          a2 += __shfl_xor(a2, off);
        }
        if (m == 0) {
          atomicAdd(&sums_out[co4 + r], a);
          atomicAdd(&sums_out[Cout + co4 + r], a2);
        }
      }
    }
  }
}

// ---------------- MFMA vector quantizer ----------------
__global__ __launch_bounds__(128) void k_vqm(
    const short* __restrict__ z, const short* __restrict__ cbq,
    const float* __restrict__ cb, const float* __restrict__ cc,
    short* __restrict__ zq, float* __restrict__ vq_sum)
{
  __shared__ __align__(16) short zl[64 * 264];
  __shared__ float ccl[1024];
  __shared__ int widx[64];
  __shared__ float red[128];

  int tid = threadIdx.x;
  int lane = tid & 63, wave = tid >> 6;
  int m = lane & 15, quad = lane >> 4;
  size_t px0 = (size_t)blockIdx.x * 64;

  for (int u = tid; u < 64 * 32; u += 128) {
    int px = u >> 5, o = u & 31;
    *(short8*)&zl[px * 264 + o * 8] = *(const short8*)&z[(px0 + px) * 256 + o * 8];
  }
  for (int u = tid; u < 1024; u += 128) ccl[u] = cc[u];
  __syncthreads();

  short8 bf[2][8];
  #pragma unroll
  for (int f = 0; f < 2; ++f) {
    int px = wave * 32 + f * 16 + m;
    #pragma unroll
    for (int kc = 0; kc < 8; ++kc)
      bf[f][kc] = *(const short8*)&zl[px * 264 + kc * 32 + quad * 8];
  }

  float best[2] = {3.4e38f, 3.4e38f};
  int bid[2] = {0, 0};

  for (int cg = 0; cg < 64; ++cg) {
    floatx4 acc0 = (floatx4){0.f, 0.f, 0.f, 0.f};
    floatx4 acc1 = (floatx4){0.f, 0.f, 0.f, 0.f};
    #pragma unroll
    for (int kc = 0; kc < 8; ++kc) {
      short8 af = *(const short8*)&cbq[((size_t)(cg * 8 + kc) * 64 + lane) * 8];
      acc0 = __builtin_amdgcn_mfma_f32_16x16x32_bf16(af, bf[0][kc], acc0, 0, 0, 0);
      acc1 = __builtin_amdgcn_mfma_f32_16x16x32_bf16(af, bf[1][kc], acc1, 0, 0, 0);
    }
    floatx4 c4 = *(const floatx4*)&ccl[cg * 16 + quad * 4];
    #pragma unroll
    for (int r = 0; r < 4; ++r) {
      int code = cg * 16 + quad * 4 + r;
      float s0 = c4[r] - 2.f * acc0[r];
      float s1 = c4[r] - 2.f * acc1[r];
      if (s0 < best[0]) { best[0] = s0; bid[0] = code; }
      if (s1 < best[1]) { best[1] = s1; bid[1] = code; }
    }
  }

  #pragma unroll
  for (int f = 0; f < 2; ++f) {
    float s = best[f]; int i = bid[f];
    #pragma unroll
    for (int off = 16; off <= 32; off <<= 1) {
      float s2 = __shfl_xor(s, off);
      int i2 = __shfl_xor(i, off);
      if (s2 < s || (s2 == s && i2 < i)) { s = s2; i = i2; }
    }
    if (quad == 0) widx[wave * 32 + f * 16 + m] = i;
  }
  __syncthreads();

  float local = 0.f;
  for (int px = 0; px < 64; ++px) {
    int code = widx[px];
    #pragma unroll
    for (int k = 0; k < 2; ++k) {
      int d = tid + k * 128;
      float q = cb[(size_t)code * 256 + d];
      float zv = bf2f(zl[px * 264 + d]);
      float df = q - zv;
      local += df * df;
      zq[(px0 + px) * 256 + d] = f2bf(q);
    }
  }
  red[tid] = local;
  __syncthreads();
  for (int off = 64; off > 0; off >>= 1) {
    if (tid < off) red[tid] += red[tid + off];
    __syncthreads();
  }
  if (tid == 0) atomicAdd(vq_sum, red[0]);
}

// ---------------- deconv 256->3, k4 s2 p1 (NHWC bf16 in, NCHW fp32 out) ----
__global__ __launch_bounds__(256) void k_deconv(
    const short* __restrict__ h, const short* __restrict__ wdt,
    const float* __restrict__ bias, const float* __restrict__ x,
    float* __restrict__ xr, float* __restrict__ recon_sum)
{
  __shared__ float red[256];
  int idx = blockIdx.x * 256 + threadIdx.x;
  int xc = idx & 127;
  int yc = (idx >> 7) & 127;
  int b = idx >> 14;

  int vy[2], vky[2], nvy = 0;
  int ky0 = (yc + 1) & 1;
  #pragma unroll
  for (int t = 0; t < 2; ++t) {
    int ky = ky0 + 2 * t;
    int iy = (yc + 1 - ky) >> 1;
    if (iy >= 0 && iy < 64) { vky[nvy] = ky; vy[nvy] = iy; ++nvy; }
  }
  int vx[2], vkx[2], nvx = 0;
  int kx0 = (xc + 1) & 1;
  #pragma unroll
  for (int t = 0; t < 2; ++t) {
    int kx = kx0 + 2 * t;
    int ix = (xc + 1 - kx) >> 1;
    if (ix >= 0 && ix < 64) { vkx[nvx] = kx; vx[nvx] = ix; ++nvx; }
  }

  float acc[3] = {bias[0], bias[1], bias[2]};
  for (int ty = 0; ty < nvy; ++ty)
    for (int tx = 0; tx < nvx; ++tx) {
      int kk = vky[ty] * 4 + vkx[tx];
      const short* hp = h + ((size_t)((b * 64 + vy[ty]) * 64 + vx[tx])) * 256;
      const short* wp = wdt + kk * 768;
      for (int c = 0; c < 256; c += 8) {
        short8 hv = *(const short8*)&hp[c];
        short8 w0 = *(const short8*)&wp[c];
        short8 w1 = *(const short8*)&wp[256 + c];
        short8 w2 = *(const short8*)&wp[512 + c];
        #pragma unroll
        for (int i = 0; i < 8; ++i) {
          float hf = bf2f(hv[i]);
          acc[0] += hf * bf2f(w0[i]);
          acc[1] += hf * bf2f(w1[i]);
          acc[2] += hf * bf2f(w2[i]);
        }
      }
    }

  float local = 0.f;
  #pragma unroll
  for (int o = 0; o < 3; ++o) {
    size_t oi = ((size_t)(b * 3 + o) * 128 + yc) * 128 + xc;
    xr[oi] = acc[o];
    float df = acc[o] - x[oi];
    local += df * df;
  }
  red[threadIdx.x] = local;
  __syncthreads();
  for (int off = 128; off > 0; off >>= 1) {
    if (threadIdx.x < off) red[threadIdx.x] += red[threadIdx.x + off];
    __syncthreads();
  }
  if (threadIdx.x == 0) atomicAdd(recon_sum, red[0]);
}

// ---------------- finalize ----------------
__global__ void k_finalize(const float* __restrict__ a, float* __restrict__ out)
{
  float e = a[0] * (1.f / (32768.f * 256.f));
  float recon = a[1] * (1.f / 393216.f);
  out[393216] = recon + 1.25f * e;
  out[393217] = recon;
}

// ---------------------------------------------------------------------------
extern "C" void kernel_launch(void* const* d_in, const int* in_sizes, int n_in,
                              void* d_out, int out_size, void* d_ws, size_t ws_size,
                              hipStream_t stream)
{
  const float* x    = (const float*)d_in[0];
  const float* ec0w = (const float*)d_in[1];
  const float* ec0b = (const float*)d_in[2];
  const float* bn0g = (const float*)d_in[3];
  const float* bn0b = (const float*)d_in[4];
  const float* ec1w = (const float*)d_in[5];
  const float* ec1b = (const float*)d_in[6];
  const float* bn1g = (const float*)d_in[7];
  const float* bn1b = (const float*)d_in[8];
  const float* ec2w = (const float*)d_in[9];
  const float* ec2b = (const float*)d_in[10];
  const float* erw1 = (const float*)d_in[11];
  const float* erb1 = (const float*)d_in[12];
  const float* erw2 = (const float*)d_in[13];
  const float* erb2 = (const float*)d_in[14];
  const float* ec3w = (const float*)d_in[15];
  const float* ec3b = (const float*)d_in[16];
  const float* cb   = (const float*)d_in[17];
  const float* dc0w = (const float*)d_in[18];
  const float* dc0b = (const float*)d_in[19];
  const float* drw1 = (const float*)d_in[20];
  const float* drb1 = (const float*)d_in[21];
  const float* drw2 = (const float*)d_in[22];
  const float* drb2 = (const float*)d_in[23];
  const float* dc1w = (const float*)d_in[24];
  const float* dc1b = (const float*)d_in[25];
  const float* ddw  = (const float*)d_in[26];
  const float* ddb  = (const float*)d_in[27];

  short* wsu = (short*)d_ws;
  short* wq_ec1 = wsu;                       // 1,179,648
  short* wq_ec2 = wsu + 1179648;             // 2,359,296
  short* wq_ec3 = wsu + 3538944;             // 1,179,648
  short* wq_dc0 = wsu + 4718592;             // 1,179,648
  short* wq_dc1 = wsu + 5898240;             // 1,179,648
  short* wq_er1 = wsu + 7077888;             // 16 x 589,824
  short* wq_er2 = wsu + 16515072;            // 16 x 65,536
  short* wq_dr1 = wsu + 17563648;            // 16 x 589,824
  short* wq_dr2 = wsu + 27000832;            // 16 x 65,536
  short* wq_dd  = wsu + 28049408;            // 12,288
  short* cbq    = wsu + 28061696;            // 262,144
  short* wq0    = wsu + 28323840;            // 16,384 (conv0 A-frags, K pad 64)
  short* im2c   = wsu + 28340224;            // 2,097,152 ([32768][64])
  short* bufA   = wsu + 30437376;            // 16,777,216 (NHWC, C<=512)
  short* bufB   = wsu + 47214592;            // 16,777,216
  short* bufZ   = wsu + 63991808;            //  8,388,608 (C=256)
  short* scr    = wsu + 72380416;            // 16,777,216 (4 x bf16 split quarters)
  float* stats  = (float*)(wsu + 89157632);
  float* bn0_sums = stats;                   // 512
  float* bn1_sums = stats + 512;             // 1024
  float* accums   = stats + 1536;            // 2
  float* bn0_ss   = stats + 1664;            // 512
  float* bn1_ss   = stats + 2176;            // 1024
  float* ccn      = stats + 3200;            // 1024

  k_init<<<1, 256, 0, stream>>>(stats);

  // ---- weight swizzles ----
  k_wswz0m<<<64, 256, 0, stream>>>(ec0w, wq0);
  k_wswz_dd<<<48, 256, 0, stream>>>(ddw, wq_dd);
  k_ccn<<<4, 256, 0, stream>>>(cb, ccn);
  k_wswz<<<1024, 256, 0, stream>>>(cb, cbq, 256, 1, 262144);
  k_wswz<<<4608, 256, 0, stream>>>(ec1w, wq_ec1, 256, 9, 1179648);
  k_wswz<<<9216, 256, 0, stream>>>(ec2w, wq_ec2, 512, 9, 2359296);
  k_wswz<<<4608, 256, 0, stream>>>(ec3w, wq_ec3, 512, 9, 1179648);
  k_wswz<<<4608, 256, 0, stream>>>(dc0w, wq_dc0, 256, 9, 1179648);
  k_wswz<<<4608, 256, 0, stream>>>(dc1w, wq_dc1, 512, 9, 1179648);
  k_wswz<<<dim3(2304, 16), 256, 0, stream>>>(erw1, wq_er1, 512, 9, 589824);
  k_wswz<<<dim3(256, 16), 256, 0, stream>>>(erw2, wq_er2, 128, 1, 65536);
  k_wswz<<<dim3(2304, 16), 256, 0, stream>>>(drw1, wq_dr1, 512, 9, 589824);
  k_wswz<<<dim3(256, 16), 256, 0, stream>>>(drw2, wq_dr2, 128, 1, 65536);

  // ---- encoder ----
  k_im2col<<<8192, 256, 0, stream>>>(x, im2c);
  // conv0: raw output + bn0 stats fused in epilogue
  k_mconv<1><<<dim3(2, 32, 8), 256, 0, stream>>>(im2c, bufA, nullptr, nullptr, nullptr,
                                                 nullptr, bn0_sums,
                                                 wq0, ec0b, 64, 0, 2, 256, F_STATS);
  k_bnfin<<<1, 512, 0, stream>>>(bn0_sums, bn0g, bn0b, bn0_ss, 256);
  // ec1: bn0 applied at staging; raw output + bn1 stats fused
  k_mconv<3><<<dim3(4, 32, 8), 256, 0, stream>>>(bufA, bufB, nullptr, nullptr, nullptr,
                                                 bn0_ss, bn1_sums,
                                                 wq_ec1, ec1b, 256, 0, 8, 512,
                                                 F_IN_BNORM | F_STATS);
  k_bnfin<<<1, 512, 0, stream>>>(bn1_sums, bn1g, bn1b, bn1_ss, 512);
  // ec2: bn1 applied at staging
  k_mconv<3><<<dim3(4, 32, 8), 256, 0, stream>>>(bufB, bufA, nullptr, nullptr, nullptr,
                                                 bn1_ss, nullptr,
                                                 wq_ec2, ec2b, 512, 0, 16, 512, F_IN_BNORM);

  for (int l = 0; l < 16; ++l) {
    k_mconv<3><<<dim3(4, 32, 8), 256, 0, stream>>>(bufA, nullptr, scr, nullptr, nullptr,
                                                   nullptr, nullptr,
                                                   wq_er1 + (size_t)l * 589824, nullptr,
                                                   512, 0, 0, 128, F_IN_RELU | F_SPLIT);
    k_mconv<1><<<dim3(4, 32, 8), 256, 0, stream>>>(nullptr, bufA, nullptr, scr,
                                                   erb1 + l * 128, nullptr, nullptr,
                                                   wq_er2 + (size_t)l * 65536, erb2 + l * 512,
                                                   128, 0, 4, 512,
                                                   F_COMB4 | F_RESIDUAL | (((l & 3) == 3) ? F_OUT_RELU : 0));
  }
  k_mconv<3><<<dim3(2, 32, 8), 256, 0, stream>>>(bufA, bufZ, nullptr, nullptr, nullptr,
                                                 nullptr, nullptr,
                                                 wq_ec3, ec3b, 512, 0, 16, 256, 0);

  // ---- VQ ----
  k_vqm<<<512, 128, 0, stream>>>(bufZ, cbq, cb, ccn, bufB, accums + 0);

  // ---- decoder ----
  k_mconv<3><<<dim3(4, 32, 8), 256, 0, stream>>>(bufB, bufA, nullptr, nullptr, nullptr,
                                                 nullptr, nullptr,
                                                 wq_dc0, dc0b, 256, 0, 8, 512, 0);
  for (int l = 0; l < 16; ++l) {
    k_mconv<3><<<dim3(4, 32, 8), 256, 0, stream>>>(bufA, nullptr, scr, nullptr, nullptr,
                                                   nullptr, nullptr,
                                                   wq_dr1 + (size_t)l * 589824, nullptr,
                                                   512, 0, 0, 128, F_IN_RELU | F_SPLIT);
    k_mconv<1><<<dim3(4, 32, 8), 256, 0, stream>>>(nullptr, bufA, nullptr, scr,
                                                   drb1 + l * 128, nullptr, nullptr,
                                                   wq_dr2 + (size_t)l * 65536, drb2 + l * 512,
                                                   128, 0, 4, 512,
                                                   F_COMB4 | F_RESIDUAL | (((l & 3) == 3) ? F_OUT_RELU : 0));
  }
  k_mconv<3><<<dim3(2, 32, 8), 256, 0, stream>>>(bufA, bufB, nullptr, nullptr, nullptr,
                                                 nullptr, nullptr,
                                                 wq_dc1, dc1b, 512, 0, 16, 256, F_OUT_RELU);

  // ---- deconv + losses ----
  k_deconv<<<512, 256, 0, stream>>>(bufB, wq_dd, ddb, x, (float*)d_out, accums + 1);
  k_finalize<<<1, 1, 0, stream>>>(accums, (float*)d_out);
}

// Round 6
// 4239.714 us; speedup vs baseline: 1.2036x; 1.2036x over previous
//
#include <hip/hip_runtime.h>
#include <cstddef>

#define F_IN_RELU    1
#define F_OUT_RELU   2
#define F_RESIDUAL   4
#define F_COMB       8
#define F_SPLIT      16
#define F_IN_BNORM   32
#define F_STATS      64

typedef __attribute__((ext_vector_type(8))) short short8;
typedef __attribute__((ext_vector_type(4))) short short4v;
typedef __attribute__((ext_vector_type(4))) float floatx4;

__device__ inline float bf2f(short h) {
  union { unsigned int u; float f; } v;
  v.u = ((unsigned int)(unsigned short)h) << 16;
  return v.f;
}
__device__ inline short f2bf(float f) {
  union { float f; unsigned int u; } v; v.f = f;
  unsigned int r = v.u + 0x7fffu + ((v.u >> 16) & 1u);
  return (short)(r >> 16);
}

// ---------------- init: zero bn sums + loss accumulators ----------------
__global__ void k_init(float* p) {
  for (int i = threadIdx.x; i < 1664; i += 256) p[i] = 0.f;
}

// ---------------- weight swizzles ----------------
// fp32 w[Cout][Cin][K][K] -> bf16 wq[co_grp16][kk][ci_chunk32][lane64][8]
__global__ __launch_bounds__(256) void k_wswz(
    const float* __restrict__ w, short* __restrict__ wq,
    int Cin, int K2, int per_layer)
{
  int idx = blockIdx.x * 256 + threadIdx.x;
  if (idx >= per_layer) return;
  int layer = blockIdx.y;
  w  += (size_t)layer * per_layer;
  wq += (size_t)layer * per_layer;
  int nch = Cin >> 5;
  int j = idx & 7;
  int lane = (idx >> 3) & 63;
  int r = idx >> 9;
  int cich = r % nch; int r2 = r / nch;
  int kk = r2 % K2;   int co_grp = r2 / K2;
  int co = co_grp * 16 + (lane & 15);
  int ci = (cich << 5) + ((lane >> 4) << 3) + j;
  wq[idx] = f2bf(w[((size_t)co * Cin + ci) * K2 + kk]);
}

// conv0 weights -> A-frag layout with K padded 48->64
__global__ __launch_bounds__(256) void k_wswz0m(
    const float* __restrict__ w, short* __restrict__ wq)
{
  int idx = blockIdx.x * 256 + threadIdx.x;
  if (idx >= 16384) return;
  int co = idx >> 6, k = idx & 63;
  float val = (k < 48) ? w[co * 48 + k] : 0.f;
  int cich = k >> 5;
  int lane = (((k >> 3) & 3) << 4) | (co & 15);
  int j = k & 7;
  int cg = co >> 4;
  wq[((size_t)(cg * 2 + cich) * 64 + lane) * 8 + j] = f2bf(val);
}

// im2col for conv0: out[px][64] bf16, k = ci*16+ky*4+kx, padded with zeros
__global__ __launch_bounds__(256) void k_im2col(
    const float* __restrict__ x, short* __restrict__ out)
{
  int idx = blockIdx.x * 256 + threadIdx.x;
  int k = idx & 63;
  int px = idx >> 6;
  int b = px >> 12;
  int rem = px & 4095;
  int y = rem >> 6, xc = rem & 63;
  int ci = k >> 4, t = k & 15;
  int ky = t >> 2, kx = t & 3;
  float v = 0.f;
  if (ci < 3) {
    int iy = 2 * y - 1 + ky, ix = 2 * xc - 1 + kx;
    if ((unsigned)iy < 128u && (unsigned)ix < 128u)
      v = x[((b * 3 + ci) * 128 + iy) * 128 + ix];
  }
  out[idx] = f2bf(v);
}

// deconv weights: w[ci][o][kk(16)] -> bf16 wdt[kk][o][ci]
__global__ __launch_bounds__(256) void k_wswz_dd(
    const float* __restrict__ w, short* __restrict__ wdt)
{
  int idx = blockIdx.x * 256 + threadIdx.x;
  if (idx >= 12288) return;
  int ci = idx & 255, t = idx >> 8;
  int o = t % 3, kk = t / 3;
  wdt[idx] = f2bf(w[(ci * 3 + o) * 16 + kk]);
}

// codebook norms |c|^2
__global__ __launch_bounds__(256) void k_ccn(
    const float* __restrict__ cb, float* __restrict__ cc)
{
  int code = blockIdx.x * 256 + threadIdx.x;
  const float4* r = (const float4*)(cb + (size_t)code * 256);
  float s = 0.f;
  for (int i = 0; i < 64; ++i) {
    float4 v = r[i];
    s += v.x * v.x + v.y * v.y + v.z * v.z + v.w * v.w;
  }
  cc[code] = s;
}

// finalize BN: scale/shift from sums
__global__ __launch_bounds__(512) void k_bnfin(
    const float* __restrict__ sums, const float* __restrict__ g,
    const float* __restrict__ beta, float* __restrict__ ss, int C)
{
  int c = threadIdx.x;
  if (c >= C) return;
  float m = sums[c] * (1.f / 32768.f);
  float var = sums[C + c] * (1.f / 32768.f) - m * m;
  float sc = g[c] * rsqrtf(var + 1e-5f);
  ss[c] = sc;
  ss[C + c] = beta[c] - m * sc;
}

// ---------------- MFMA implicit-GEMM conv, NHWC bf16 ----------------
// Block: 256 thr = 4 waves = (2 rows) x (2 co-halves); wave tile 64co x 64px.
// Grid: (Cout/128 or K-split2, 32 y-pairs, 8 b).
template <int K>
__global__ __launch_bounds__(256) void k_mconv(
    const short* __restrict__ in, short* __restrict__ out,
    short* __restrict__ outf,
    const short* __restrict__ scr2,
    const float* __restrict__ bias_t,
    const float* __restrict__ ss_in, float* __restrict__ sums_out,
    const short* __restrict__ wq, const float* __restrict__ bias,
    int Cin, int c0, int c1, int Cout, int flags)
{
  constexpr int K2 = K * K;
  constexpr int XS = 40;                 // padded x stride (ushorts)
  constexpr int NR = (K == 3) ? 4 : 1;
  constexpr int NX = (K == 3) ? 66 : 128;
  __shared__ __align__(16) short s_in[NR * NX * XS];
  __shared__ float btl[128];
  __shared__ float ssl[1024];

  int tid = threadIdx.x;
  int lane = tid & 63;
  int wave = tid >> 6;
  int m = lane & 15, quad = lane >> 4;
  int wr = wave >> 1, wc = wave & 1;
  int y2 = blockIdx.y * 2, b = blockIdx.z;
  int coblk = (flags & F_SPLIT) ? 0 : blockIdx.x;
  int nch = Cin >> 5;

  if ((flags & F_COMB) && tid < 128) btl[tid] = bias_t[tid];
  if (flags & F_IN_BNORM) {
    for (int u = tid; u < 2 * Cin; u += 256) ssl[u] = ss_in[u];
  }

  int cc0 = c0, cc1 = c1;
  if (flags & F_SPLIT) {
    int half = nch >> 1;
    cc0 = blockIdx.x * half; cc1 = cc0 + half;
    outf += (size_t)blockIdx.x * 4194304;
  }

  floatx4 acc[4][4];
  #pragma unroll
  for (int f = 0; f < 4; ++f)
    #pragma unroll
    for (int p = 0; p < 4; ++p) acc[f][p] = (floatx4){0.f, 0.f, 0.f, 0.f};

  for (int cich = cc0; cich < cc1; ++cich) {
    __syncthreads();
    if (K == 3) {
      for (int u = tid; u < 4 * 66 * 4; u += 256) {
        int o = u & 3; int t2 = u >> 2;
        int xp = t2 % 66; int row = t2 / 66;
        int gy = y2 - 1 + row, gx = xp - 1;
        int ch = (cich << 5) + (o << 3);
        short8 v = {0, 0, 0, 0, 0, 0, 0, 0};
        if ((unsigned)gy < 64u && (unsigned)gx < 64u)
          v = *(const short8*)&in[((size_t)((b * 64 + gy) * 64 + gx)) * Cin + ch];
        if (flags & F_IN_BNORM) {
          #pragma unroll
          for (int i = 0; i < 8; ++i) {
            float f2 = bf2f(v[i]) * ssl[ch + i] + ssl[Cin + ch + i];
            v[i] = f2bf(f2 > 0.f ? f2 : 0.f);
          }
        } else if (flags & F_IN_RELU) {
          #pragma unroll
          for (int i = 0; i < 8; ++i) if (v[i] < 0) v[i] = 0;
        }
        *(short8*)&s_in[(row * 66 + xp) * XS + (o << 3)] = v;
      }
    } else {
      if (flags & F_COMB) {
        for (int u = tid; u < 512; u += 256) {
          int o = u & 3; int xp = u >> 2;
          int ch = (cich << 5) + (o << 3);
          size_t base = ((size_t)((b * 64 + y2) * 64 + xp)) * 128 + ch;
          float va[8];
          #pragma unroll
          for (int i = 0; i < 8; ++i) va[i] = btl[ch + i];
          #pragma unroll
          for (int q = 0; q < 2; ++q) {
            short8 aq = *(const short8*)&scr2[(size_t)q * 4194304 + base];
            #pragma unroll
            for (int i = 0; i < 8; ++i) va[i] += bf2f(aq[i]);
          }
          short8 v;
          #pragma unroll
          for (int i = 0; i < 8; ++i) v[i] = f2bf(va[i] > 0.f ? va[i] : 0.f);
          *(short8*)&s_in[xp * XS + (o << 3)] = v;
        }
      } else {
        for (int u = tid; u < 512; u += 256) {
          int o = u & 3; int xp = u >> 2;
          short8 v = *(const short8*)&in[((size_t)((b * 64 + y2) * 64 + xp)) * Cin + (cich << 5) + (o << 3)];
          if (flags & F_IN_RELU) {
            #pragma unroll
            for (int i = 0; i < 8; ++i) if (v[i] < 0) v[i] = 0;
          }
          *(short8*)&s_in[xp * XS + (o << 3)] = v;
        }
      }
    }
    __syncthreads();

    #pragma unroll
    for (int kk = 0; kk < K2; ++kk) {
      int ky = (K == 3) ? (kk / 3) : 0;
      int kx = (K == 3) ? (kk - ky * 3) : 0;
      short8 af[4];
      #pragma unroll
      for (int f = 0; f < 4; ++f) {
        int cg = coblk * 8 + wc * 4 + f;
        af[f] = *(const short8*)&wq[(((size_t)(cg * K2 + kk) * nch + cich) * 64 + lane) * 8];
      }
      #pragma unroll
      for (int p = 0; p < 4; ++p) {
        short8 bv;
        if (K == 3)
          bv = *(const short8*)&s_in[((wr + ky) * 66 + p * 16 + m + kx) * XS + (quad << 3)];
        else
          bv = *(const short8*)&s_in[(wr * 64 + p * 16 + m) * XS + (quad << 3)];
        #pragma unroll
        for (int f = 0; f < 4; ++f)
          acc[f][p] = __builtin_amdgcn_mfma_f32_16x16x32_bf16(af[f], bv, acc[f][p], 0, 0, 0);
      }
    }
  }

  int pixrow = (b * 64 + y2 + wr) * 64;

  if (flags & F_SPLIT) {
    #pragma unroll
    for (int f = 0; f < 4; ++f) {
      int co_l = wc * 64 + f * 16 + quad * 4;
      #pragma unroll
      for (int p = 0; p < 4; ++p) {
        int x = p * 16 + m;
        short4v sv;
        #pragma unroll
        for (int r = 0; r < 4; ++r) sv[r] = f2bf(acc[f][p][r]);
        *(short4v*)&outf[(size_t)(pixrow + x) * 128 + co_l] = sv;
      }
    }
    return;
  }

  #pragma unroll
  for (int f = 0; f < 4; ++f) {
    int co4 = coblk * 128 + wc * 64 + f * 16 + quad * 4;
    floatx4 bv4 = *(const floatx4*)&bias[co4];
    float sv1[4] = {0.f, 0.f, 0.f, 0.f};
    float sv2[4] = {0.f, 0.f, 0.f, 0.f};
    #pragma unroll
    for (int p = 0; p < 4; ++p) {
      int x = p * 16 + m;
      size_t oidx = (size_t)(pixrow + x) * Cout + co4;
      float v[4];
      #pragma unroll
      for (int r = 0; r < 4; ++r) v[r] = acc[f][p][r] + bv4[r];
      if (flags & F_RESIDUAL) {
        short4v rr = *(const short4v*)&out[oidx];
        #pragma unroll
        for (int r = 0; r < 4; ++r) v[r] += bf2f(rr[r]);
      }
      if (flags & F_OUT_RELU) {
        #pragma unroll
        for (int r = 0; r < 4; ++r) v[r] = v[r] > 0.f ? v[r] : 0.f;
      }
      if (flags & F_STATS) {
        #pragma unroll
        for (int r = 0; r < 4; ++r) { sv1[r] += v[r]; sv2[r] += v[r] * v[r]; }
      }
      short4v sv;
      #pragma unroll
      for (int r = 0; r < 4; ++r) sv[r] = f2bf(v[r]);
      *(short4v*)&out[oidx] = sv;
    }
    if (flags & F_STATS) {
      #pragma unroll
      for (int r = 0; r < 4; ++r) {
        float a = sv1[r], a2 = sv2[r];
        #pragma unroll
        for (int off = 1; off <= 8; off <<= 1) {
          a += __shfl_xor(a, off);
          a2 += __shfl_xor(a2, off);
        }
        if (m == 0) {
          atomicAdd(&sums_out[co4 + r], a);
          atomicAdd(&sums_out[Cout + co4 + r], a2);
        }
      }
    }
  }
}

// ---------------- MFMA vector quantizer ----------------
__global__ __launch_bounds__(128) void k_vqm(
    const short* __restrict__ z, const short* __restrict__ cbq,
    const float* __restrict__ cb, const float* __restrict__ cc,
    short* __restrict__ zq, float* __restrict__ vq_sum)
{
  __shared__ __align__(16) short zl[64 * 264];
  __shared__ float ccl[1024];
  __shared__ int widx[64];
  __shared__ float red[128];

  int tid = threadIdx.x;
  int lane = tid & 63, wave = tid >> 6;
  int m = lane & 15, quad = lane >> 4;
  size_t px0 = (size_t)blockIdx.x * 64;

  for (int u = tid; u < 64 * 32; u += 128) {
    int px = u >> 5, o = u & 31;
    *(short8*)&zl[px * 264 + o * 8] = *(const short8*)&z[(px0 + px) * 256 + o * 8];
  }
  for (int u = tid; u < 1024; u += 128) ccl[u] = cc[u];
  __syncthreads();

  short8 bf[2][8];
  #pragma unroll
  for (int f = 0; f < 2; ++f) {
    int px = wave * 32 + f * 16 + m;
    #pragma unroll
    for (int kc = 0; kc < 8; ++kc)
      bf[f][kc] = *(const short8*)&zl[px * 264 + kc * 32 + quad * 8];
  }

  float best[2] = {3.4e38f, 3.4e38f};
  int bid[2] = {0, 0};

  for (int cg = 0; cg < 64; ++cg) {
    floatx4 acc0 = (floatx4){0.f, 0.f, 0.f, 0.f};
    floatx4 acc1 = (floatx4){0.f, 0.f, 0.f, 0.f};
    #pragma unroll
    for (int kc = 0; kc < 8; ++kc) {
      short8 af = *(const short8*)&cbq[((size_t)(cg * 8 + kc) * 64 + lane) * 8];
      acc0 = __builtin_amdgcn_mfma_f32_16x16x32_bf16(af, bf[0][kc], acc0, 0, 0, 0);
      acc1 = __builtin_amdgcn_mfma_f32_16x16x32_bf16(af, bf[1][kc], acc1, 0, 0, 0);
    }
    floatx4 c4 = *(const floatx4*)&ccl[cg * 16 + quad * 4];
    #pragma unroll
    for (int r = 0; r < 4; ++r) {
      int code = cg * 16 + quad * 4 + r;
      float s0 = c4[r] - 2.f * acc0[r];
      float s1 = c4[r] - 2.f * acc1[r];
      if (s0 < best[0]) { best[0] = s0; bid[0] = code; }
      if (s1 < best[1]) { best[1] = s1; bid[1] = code; }
    }
  }

  #pragma unroll
  for (int f = 0; f < 2; ++f) {
    float s = best[f]; int i = bid[f];
    #pragma unroll
    for (int off = 16; off <= 32; off <<= 1) {
      float s2 = __shfl_xor(s, off);
      int i2 = __shfl_xor(i, off);
      if (s2 < s || (s2 == s && i2 < i)) { s = s2; i = i2; }
    }
    if (quad == 0) widx[wave * 32 + f * 16 + m] = i;
  }
  __syncthreads();

  float local = 0.f;
  for (int px = 0; px < 64; ++px) {
    int code = widx[px];
    #pragma unroll
    for (int k = 0; k < 2; ++k) {
      int d = tid + k * 128;
      float q = cb[(size_t)code * 256 + d];
      float zv = bf2f(zl[px * 264 + d]);
      float df = q - zv;
      local += df * df;
      zq[(px0 + px) * 256 + d] = f2bf(q);
    }
  }
  red[tid] = local;
  __syncthreads();
  for (int off = 64; off > 0; off >>= 1) {
    if (tid < off) red[tid] += red[tid + off];
    __syncthreads();
  }
  if (tid == 0) atomicAdd(vq_sum, red[0]);
}

// ---------------- deconv 256->3, k4 s2 p1 (NHWC bf16 in, NCHW fp32 out) ----
__global__ __launch_bounds__(256) void k_deconv(
    const short* __restrict__ h, const short* __restrict__ wdt,
    const float* __restrict__ bias, const float* __restrict__ x,
    float* __restrict__ xr, float* __restrict__ recon_sum)
{
  __shared__ float red[256];
  int idx = blockIdx.x * 256 + threadIdx.x;
  int xc = idx & 127;
  int yc = (idx >> 7) & 127;
  int b = idx >> 14;

  int vy[2], vky[2], nvy = 0;
  int ky0 = (yc + 1) & 1;
  #pragma unroll
  for (int t = 0; t < 2; ++t) {
    int ky = ky0 + 2 * t;
    int iy = (yc + 1 - ky) >> 1;
    if (iy >= 0 && iy < 64) { vky[nvy] = ky; vy[nvy] = iy; ++nvy; }
  }
  int vx[2], vkx[2], nvx = 0;
  int kx0 = (xc + 1) & 1;
  #pragma unroll
  for (int t = 0; t < 2; ++t) {
    int kx = kx0 + 2 * t;
    int ix = (xc + 1 - kx) >> 1;
    if (ix >= 0 && ix < 64) { vkx[nvx] = kx; vx[nvx] = ix; ++nvx; }
  }

  float acc[3] = {bias[0], bias[1], bias[2]};
  for (int ty = 0; ty < nvy; ++ty)
    for (int tx = 0; tx < nvx; ++tx) {
      int kk = vky[ty] * 4 + vkx[tx];
      const short* hp = h + ((size_t)((b * 64 + vy[ty]) * 64 + vx[tx])) * 256;
      const short* wp = wdt + kk * 768;
      for (int c = 0; c < 256; c += 8) {
        short8 hv = *(const short8*)&hp[c];
        short8 w0 = *(const short8*)&wp[c];
        short8 w1 = *(const short8*)&wp[256 + c];
        short8 w2 = *(const short8*)&wp[512 + c];
        #pragma unroll
        for (int i = 0; i < 8; ++i) {
          float hf = bf2f(hv[i]);
          acc[0] += hf * bf2f(w0[i]);
          acc[1] += hf * bf2f(w1[i]);
          acc[2] += hf * bf2f(w2[i]);
        }
      }
    }

  float local = 0.f;
  #pragma unroll
  for (int o = 0; o < 3; ++o) {
    size_t oi = ((size_t)(b * 3 + o) * 128 + yc) * 128 + xc;
    xr[oi] = acc[o];
    float df = acc[o] - x[oi];
    local += df * df;
  }
  red[threadIdx.x] = local;
  __syncthreads();
  for (int off = 128; off > 0; off >>= 1) {
    if (threadIdx.x < off) red[threadIdx.x] += red[threadIdx.x + off];
    __syncthreads();
  }
  if (threadIdx.x == 0) atomicAdd(recon_sum, red[0]);
}

// ---------------- finalize ----------------
__global__ void k_finalize(const float* __restrict__ a, float* __restrict__ out)
{
  float e = a[0] * (1.f / (32768.f * 256.f));
  float recon = a[1] * (1.f / 393216.f);
  out[393216] = recon + 1.25f * e;
  out[393217] = recon;
}

// ---------------------------------------------------------------------------
extern "C" void kernel_launch(void* const* d_in, const int* in_sizes, int n_in,
                              void* d_out, int out_size, void* d_ws, size_t ws_size,
                              hipStream_t stream)
{
  const float* x    = (const float*)d_in[0];
  const float* ec0w = (const float*)d_in[1];
  const float* ec0b = (const float*)d_in[2];
  const float* bn0g = (const float*)d_in[3];
  const float* bn0b = (const float*)d_in[4];
  const float* ec1w = (const float*)d_in[5];
  const float* ec1b = (const float*)d_in[6];
  const float* bn1g = (const float*)d_in[7];
  const float* bn1b = (const float*)d_in[8];
  const float* ec2w = (const float*)d_in[9];
  const float* ec2b = (const float*)d_in[10];
  const float* erw1 = (const float*)d_in[11];
  const float* erb1 = (const float*)d_in[12];
  const float* erw2 = (const float*)d_in[13];
  const float* erb2 = (const float*)d_in[14];
  const float* ec3w = (const float*)d_in[15];
  const float* ec3b = (const float*)d_in[16];
  const float* cb   = (const float*)d_in[17];
  const float* dc0w = (const float*)d_in[18];
  const float* dc0b = (const float*)d_in[19];
  const float* drw1 = (const float*)d_in[20];
  const float* drb1 = (const float*)d_in[21];
  const float* drw2 = (const float*)d_in[22];
  const float* drb2 = (const float*)d_in[23];
  const float* dc1w = (const float*)d_in[24];
  const float* dc1b = (const float*)d_in[25];
  const float* ddw  = (const float*)d_in[26];
  const float* ddb  = (const float*)d_in[27];

  short* wsu = (short*)d_ws;
  short* wq_ec1 = wsu;                       // 1,179,648
  short* wq_ec2 = wsu + 1179648;             // 2,359,296
  short* wq_ec3 = wsu + 3538944;             // 1,179,648
  short* wq_dc0 = wsu + 4718592;             // 1,179,648
  short* wq_dc1 = wsu + 5898240;             // 1,179,648
  short* wq_er1 = wsu + 7077888;             // 16 x 589,824
  short* wq_er2 = wsu + 16515072;            // 16 x 65,536
  short* wq_dr1 = wsu + 17563648;            // 16 x 589,824
  short* wq_dr2 = wsu + 27000832;            // 16 x 65,536
  short* wq_dd  = wsu + 28049408;            // 12,288
  short* cbq    = wsu + 28061696;            // 262,144
  short* wq0    = wsu + 28323840;            // 16,384 (conv0 A-frags, K pad 64)
  short* im2c   = wsu + 28340224;            // 2,097,152 ([32768][64])
  short* bufA   = wsu + 30437376;            // 16,777,216 (NHWC, C<=512)
  short* bufB   = wsu + 47214592;            // 16,777,216
  short* bufZ   = wsu + 63991808;            //  8,388,608 (C=256)
  short* scr    = wsu + 72380416;            //  8,388,608 (2 x bf16 split halves)
  float* stats  = (float*)(wsu + 80769024);
  float* bn0_sums = stats;                   // 512
  float* bn1_sums = stats + 512;             // 1024
  float* accums   = stats + 1536;            // 2
  float* bn0_ss   = stats + 1664;            // 512
  float* bn1_ss   = stats + 2176;            // 1024
  float* ccn      = stats + 3200;            // 1024

  k_init<<<1, 256, 0, stream>>>(stats);

  // ---- weight swizzles ----
  k_wswz0m<<<64, 256, 0, stream>>>(ec0w, wq0);
  k_wswz_dd<<<48, 256, 0, stream>>>(ddw, wq_dd);
  k_ccn<<<4, 256, 0, stream>>>(cb, ccn);
  k_wswz<<<1024, 256, 0, stream>>>(cb, cbq, 256, 1, 262144);
  k_wswz<<<4608, 256, 0, stream>>>(ec1w, wq_ec1, 256, 9, 1179648);
  k_wswz<<<9216, 256, 0, stream>>>(ec2w, wq_ec2, 512, 9, 2359296);
  k_wswz<<<4608, 256, 0, stream>>>(ec3w, wq_ec3, 512, 9, 1179648);
  k_wswz<<<4608, 256, 0, stream>>>(dc0w, wq_dc0, 256, 9, 1179648);
  k_wswz<<<4608, 256, 0, stream>>>(dc1w, wq_dc1, 512, 9, 1179648);
  k_wswz<<<dim3(2304, 16), 256, 0, stream>>>(erw1, wq_er1, 512, 9, 589824);
  k_wswz<<<dim3(256, 16), 256, 0, stream>>>(erw2, wq_er2, 128, 1, 65536);
  k_wswz<<<dim3(2304, 16), 256, 0, stream>>>(drw1, wq_dr1, 512, 9, 589824);
  k_wswz<<<dim3(256, 16), 256, 0, stream>>>(drw2, wq_dr2, 128, 1, 65536);

  // ---- encoder ----
  k_im2col<<<8192, 256, 0, stream>>>(x, im2c);
  // conv0: raw output + bn0 stats fused in epilogue
  k_mconv<1><<<dim3(2, 32, 8), 256, 0, stream>>>(im2c, bufA, nullptr, nullptr, nullptr,
                                                 nullptr, bn0_sums,
                                                 wq0, ec0b, 64, 0, 2, 256, F_STATS);
  k_bnfin<<<1, 512, 0, stream>>>(bn0_sums, bn0g, bn0b, bn0_ss, 256);
  // ec1: bn0 applied at staging; raw output + bn1 stats fused
  k_mconv<3><<<dim3(4, 32, 8), 256, 0, stream>>>(bufA, bufB, nullptr, nullptr, nullptr,
                                                 bn0_ss, bn1_sums,
                                                 wq_ec1, ec1b, 256, 0, 8, 512,
                                                 F_IN_BNORM | F_STATS);
  k_bnfin<<<1, 512, 0, stream>>>(bn1_sums, bn1g, bn1b, bn1_ss, 512);
  // ec2: bn1 applied at staging
  k_mconv<3><<<dim3(4, 32, 8), 256, 0, stream>>>(bufB, bufA, nullptr, nullptr, nullptr,
                                                 bn1_ss, nullptr,
                                                 wq_ec2, ec2b, 512, 0, 16, 512, F_IN_BNORM);

  for (int l = 0; l < 16; ++l) {
    k_mconv<3><<<dim3(2, 32, 8), 256, 0, stream>>>(bufA, nullptr, scr, nullptr, nullptr,
                                                   nullptr, nullptr,
                                                   wq_er1 + (size_t)l * 589824, nullptr,
                                                   512, 0, 0, 128, F_IN_RELU | F_SPLIT);
    k_mconv<1><<<dim3(4, 32, 8), 256, 0, stream>>>(nullptr, bufA, nullptr, scr,
                                                   erb1 + l * 128, nullptr, nullptr,
                                                   wq_er2 + (size_t)l * 65536, erb2 + l * 512,
                                                   128, 0, 4, 512,
                                                   F_COMB | F_RESIDUAL | (((l & 3) == 3) ? F_OUT_RELU : 0));
  }
  k_mconv<3><<<dim3(2, 32, 8), 256, 0, stream>>>(bufA, bufZ, nullptr, nullptr, nullptr,
                                                 nullptr, nullptr,
                                                 wq_ec3, ec3b, 512, 0, 16, 256, 0);

  // ---- VQ ----
  k_vqm<<<512, 128, 0, stream>>>(bufZ, cbq, cb, ccn, bufB, accums + 0);

  // ---- decoder ----
  k_mconv<3><<<dim3(4, 32, 8), 256, 0, stream>>>(bufB, bufA, nullptr, nullptr, nullptr,
                                                 nullptr, nullptr,
                                                 wq_dc0, dc0b, 256, 0, 8, 512, 0);
  for (int l = 0; l < 16; ++l) {
    k_mconv<3><<<dim3(2, 32, 8), 256, 0, stream>>>(bufA, nullptr, scr, nullptr, nullptr,
                                                   nullptr, nullptr,
                                                   wq_dr1 + (size_t)l * 589824, nullptr,
                                                   512, 0, 0, 128, F_IN_RELU | F_SPLIT);
    k_mconv<1><<<dim3(4, 32, 8), 256, 0, stream>>>(nullptr, bufA, nullptr, scr,
                                                   drb1 + l * 128, nullptr, nullptr,
                                                   wq_dr2 + (size_t)l * 65536, drb2 + l * 512,
                                                   128, 0, 4, 512,
                                                   F_COMB | F_RESIDUAL | (((l & 3) == 3) ? F_OUT_RELU : 0));
  }
  k_mconv<3><<<dim3(2, 32, 8), 256, 0, stream>>>(bufA, bufB, nullptr, nullptr, nullptr,
                                                 nullptr, nullptr,
                                                 wq_dc1, dc1b, 512, 0, 16, 256, F_OUT_RELU);

  // ---- deconv + losses ----
  k_deconv<<<512, 256, 0, stream>>>(bufB, wq_dd, ddb, x, (float*)d_out, accums + 1);
  k_finalize<<<1, 1, 0, stream>>>(accums, (float*)d_out);
}

// Round 7
// 3989.957 us; speedup vs baseline: 1.2789x; 1.0626x over previous
//
#include <hip/hip_runtime.h>
#include <cstddef>

#define F_OUT_RELU   2
#define F_IN_BNORM   32
#define F_STATS      64

typedef __attribute__((ext_vector_type(8))) short short8;
typedef __attribute__((ext_vector_type(4))) short short4v;
typedef __attribute__((ext_vector_type(4))) float floatx4;

__device__ inline float bf2f(short h) {
  union { unsigned int u; float f; } v;
  v.u = ((unsigned int)(unsigned short)h) << 16;
  return v.f;
}
__device__ inline short f2bf(float f) {
  union { float f; unsigned int u; } v; v.f = f;
  unsigned int r = v.u + 0x7fffu + ((v.u >> 16) & 1u);
  return (short)(r >> 16);
}

// ---------------- init: zero bn sums + loss accumulators ----------------
__global__ void k_init(float* p) {
  for (int i = threadIdx.x; i < 1664; i += 256) p[i] = 0.f;
}

// ---------------- weight swizzles ----------------
// fp32 w[Cout][Cin][K][K] -> bf16 wq[co_grp16][kk][ci_chunk32][lane64][8]
__global__ __launch_bounds__(256) void k_wswz(
    const float* __restrict__ w, short* __restrict__ wq,
    int Cin, int K2, int per_layer)
{
  int idx = blockIdx.x * 256 + threadIdx.x;
  if (idx >= per_layer) return;
  int layer = blockIdx.y;
  w  += (size_t)layer * per_layer;
  wq += (size_t)layer * per_layer;
  int nch = Cin >> 5;
  int j = idx & 7;
  int lane = (idx >> 3) & 63;
  int r = idx >> 9;
  int cich = r % nch; int r2 = r / nch;
  int kk = r2 % K2;   int co_grp = r2 / K2;
  int co = co_grp * 16 + (lane & 15);
  int ci = (cich << 5) + ((lane >> 4) << 3) + j;
  wq[idx] = f2bf(w[((size_t)co * Cin + ci) * K2 + kk]);
}

// conv0 weights -> A-frag layout with K padded 48->64
__global__ __launch_bounds__(256) void k_wswz0m(
    const float* __restrict__ w, short* __restrict__ wq)
{
  int idx = blockIdx.x * 256 + threadIdx.x;
  if (idx >= 16384) return;
  int co = idx >> 6, k = idx & 63;
  float val = (k < 48) ? w[co * 48 + k] : 0.f;
  int cich = k >> 5;
  int lane = (((k >> 3) & 3) << 4) | (co & 15);
  int j = k & 7;
  int cg = co >> 4;
  wq[((size_t)(cg * 2 + cich) * 64 + lane) * 8 + j] = f2bf(val);
}

// im2col for conv0: out[px][64] bf16, k = ci*16+ky*4+kx, padded with zeros
__global__ __launch_bounds__(256) void k_im2col(
    const float* __restrict__ x, short* __restrict__ out)
{
  int idx = blockIdx.x * 256 + threadIdx.x;
  int k = idx & 63;
  int px = idx >> 6;
  int b = px >> 12;
  int rem = px & 4095;
  int y = rem >> 6, xc = rem & 63;
  int ci = k >> 4, t = k & 15;
  int ky = t >> 2, kx = t & 3;
  float v = 0.f;
  if (ci < 3) {
    int iy = 2 * y - 1 + ky, ix = 2 * xc - 1 + kx;
    if ((unsigned)iy < 128u && (unsigned)ix < 128u)
      v = x[((b * 3 + ci) * 128 + iy) * 128 + ix];
  }
  out[idx] = f2bf(v);
}

// deconv weights: w[ci][o][kk(16)] -> bf16 wdt[kk][o][ci]
__global__ __launch_bounds__(256) void k_wswz_dd(
    const float* __restrict__ w, short* __restrict__ wdt)
{
  int idx = blockIdx.x * 256 + threadIdx.x;
  if (idx >= 12288) return;
  int ci = idx & 255, t = idx >> 8;
  int o = t % 3, kk = t / 3;
  wdt[idx] = f2bf(w[(ci * 3 + o) * 16 + kk]);
}

// codebook norms |c|^2
__global__ __launch_bounds__(256) void k_ccn(
    const float* __restrict__ cb, float* __restrict__ cc)
{
  int code = blockIdx.x * 256 + threadIdx.x;
  const float4* r = (const float4*)(cb + (size_t)code * 256);
  float s = 0.f;
  for (int i = 0; i < 64; ++i) {
    float4 v = r[i];
    s += v.x * v.x + v.y * v.y + v.z * v.z + v.w * v.w;
  }
  cc[code] = s;
}

// finalize BN: scale/shift from sums
__global__ __launch_bounds__(512) void k_bnfin(
    const float* __restrict__ sums, const float* __restrict__ g,
    const float* __restrict__ beta, float* __restrict__ ss, int C)
{
  int c = threadIdx.x;
  if (c >= C) return;
  float m = sums[c] * (1.f / 32768.f);
  float var = sums[C + c] * (1.f / 32768.f) - m * m;
  float sc = g[c] * rsqrtf(var + 1e-5f);
  ss[c] = sc;
  ss[C + c] = beta[c] - m * sc;
}

// ---------------- MFMA implicit-GEMM conv, NHWC bf16 (big convs) ----------
// Block: 256 thr = 4 waves = (2 rows) x (2 co-halves); wave tile 64co x 64px.
template <int K>
__global__ __launch_bounds__(256) void k_mconv(
    const short* __restrict__ in, short* __restrict__ out,
    const float* __restrict__ ss_in, float* __restrict__ sums_out,
    const short* __restrict__ wq, const float* __restrict__ bias,
    int Cin, int Cout, int flags)
{
  constexpr int K2 = K * K;
  constexpr int XS = 40;
  constexpr int NR = (K == 3) ? 4 : 1;
  constexpr int NX = (K == 3) ? 66 : 128;
  __shared__ __align__(16) short s_in[NR * NX * XS];
  __shared__ float ssl[1024];

  int tid = threadIdx.x;
  int lane = tid & 63;
  int wave = tid >> 6;
  int m = lane & 15, quad = lane >> 4;
  int wr = wave >> 1, wc = wave & 1;
  int y2 = blockIdx.y * 2, b = blockIdx.z;
  int coblk = blockIdx.x;
  int nch = Cin >> 5;

  if (flags & F_IN_BNORM) {
    for (int u = tid; u < 2 * Cin; u += 256) ssl[u] = ss_in[u];
  }

  floatx4 acc[4][4];
  #pragma unroll
  for (int f = 0; f < 4; ++f)
    #pragma unroll
    for (int p = 0; p < 4; ++p) acc[f][p] = (floatx4){0.f, 0.f, 0.f, 0.f};

  for (int cich = 0; cich < nch; ++cich) {
    __syncthreads();
    if (K == 3) {
      for (int u = tid; u < 4 * 66 * 4; u += 256) {
        int o = u & 3; int t2 = u >> 2;
        int xp = t2 % 66; int row = t2 / 66;
        int gy = y2 - 1 + row, gx = xp - 1;
        int ch = (cich << 5) + (o << 3);
        short8 v = {0, 0, 0, 0, 0, 0, 0, 0};
        if ((unsigned)gy < 64u && (unsigned)gx < 64u)
          v = *(const short8*)&in[((size_t)((b * 64 + gy) * 64 + gx)) * Cin + ch];
        if (flags & F_IN_BNORM) {
          #pragma unroll
          for (int i = 0; i < 8; ++i) {
            float f2 = bf2f(v[i]) * ssl[ch + i] + ssl[Cin + ch + i];
            v[i] = f2bf(f2 > 0.f ? f2 : 0.f);
          }
        }
        *(short8*)&s_in[(row * 66 + xp) * XS + (o << 3)] = v;
      }
    } else {
      for (int u = tid; u < 512; u += 256) {
        int o = u & 3; int xp = u >> 2;
        short8 v = *(const short8*)&in[((size_t)((b * 64 + y2) * 64 + xp)) * Cin + (cich << 5) + (o << 3)];
        *(short8*)&s_in[xp * XS + (o << 3)] = v;
      }
    }
    __syncthreads();

    #pragma unroll
    for (int kk = 0; kk < K2; ++kk) {
      int ky = (K == 3) ? (kk / 3) : 0;
      int kx = (K == 3) ? (kk - ky * 3) : 0;
      short8 af[4];
      #pragma unroll
      for (int f = 0; f < 4; ++f) {
        int cg = coblk * 8 + wc * 4 + f;
        af[f] = *(const short8*)&wq[(((size_t)(cg * K2 + kk) * nch + cich) * 64 + lane) * 8];
      }
      #pragma unroll
      for (int p = 0; p < 4; ++p) {
        short8 bv;
        if (K == 3)
          bv = *(const short8*)&s_in[((wr + ky) * 66 + p * 16 + m + kx) * XS + (quad << 3)];
        else
          bv = *(const short8*)&s_in[(wr * 64 + p * 16 + m) * XS + (quad << 3)];
        #pragma unroll
        for (int f = 0; f < 4; ++f)
          acc[f][p] = __builtin_amdgcn_mfma_f32_16x16x32_bf16(af[f], bv, acc[f][p], 0, 0, 0);
      }
    }
  }

  int pixrow = (b * 64 + y2 + wr) * 64;

  #pragma unroll
  for (int f = 0; f < 4; ++f) {
    int co4 = coblk * 128 + wc * 64 + f * 16 + quad * 4;
    floatx4 bv4 = *(const floatx4*)&bias[co4];
    float sv1[4] = {0.f, 0.f, 0.f, 0.f};
    float sv2[4] = {0.f, 0.f, 0.f, 0.f};
    #pragma unroll
    for (int p = 0; p < 4; ++p) {
      int x = p * 16 + m;
      size_t oidx = (size_t)(pixrow + x) * Cout + co4;
      float v[4];
      #pragma unroll
      for (int r = 0; r < 4; ++r) v[r] = acc[f][p][r] + bv4[r];
      if (flags & F_OUT_RELU) {
        #pragma unroll
        for (int r = 0; r < 4; ++r) v[r] = v[r] > 0.f ? v[r] : 0.f;
      }
      if (flags & F_STATS) {
        #pragma unroll
        for (int r = 0; r < 4; ++r) { sv1[r] += v[r]; sv2[r] += v[r] * v[r]; }
      }
      short4v sv;
      #pragma unroll
      for (int r = 0; r < 4; ++r) sv[r] = f2bf(v[r]);
      *(short4v*)&out[oidx] = sv;
    }
    if (flags & F_STATS) {
      #pragma unroll
      for (int r = 0; r < 4; ++r) {
        float a = sv1[r], a2 = sv2[r];
        #pragma unroll
        for (int off = 1; off <= 8; off <<= 1) {
          a += __shfl_xor(a, off);
          a2 += __shfl_xor(a2, off);
        }
        if (m == 0) {
          atomicAdd(&sums_out[co4 + r], a);
          atomicAdd(&sums_out[Cout + co4 + r], a2);
        }
      }
    }
  }
}

// ---------------- fully fused residual layer (512->128 3x3, 128->512 1x1) --
// Block: 512 thr = 8 waves = (2 rows) x (4 t-co quarters).
// Grid: (32 y-pairs, 8 b). Reads hin (ping), writes hout (pong).
// t computed in fp32 (full K), relu'd, round-tripped via LDS to B-layout.
__global__ __launch_bounds__(512) void k_res(
    const short* __restrict__ hin, short* __restrict__ hout,
    const short* __restrict__ w1q, const float* __restrict__ b1,
    const short* __restrict__ w2q, const float* __restrict__ b2,
    int relu_out)
{
  constexpr int XS = 40;     // staged input x-stride (ushorts)
  constexpr int TS = 136;    // t_tile px-stride (ushorts), 272 B (16B-aligned)
  __shared__ __align__(16) short s_in[4 * 66 * XS];
  __shared__ __align__(16) short t_tile[128 * TS];

  int tid = threadIdx.x;
  int lane = tid & 63;
  int wave = tid >> 6;
  int m = lane & 15, quad = lane >> 4;
  int wr = wave >> 2;        // row within pair
  int wq_ = wave & 3;        // t-co quarter (32 ch)
  int y2 = blockIdx.x * 2, b = blockIdx.y;

  // ---- 3x3: t = relu(W1 * relu(h)) , 128 ch, fp32 acc ----
  floatx4 acc[2][4];
  #pragma unroll
  for (int f = 0; f < 2; ++f)
    #pragma unroll
    for (int p = 0; p < 4; ++p) acc[f][p] = (floatx4){0.f, 0.f, 0.f, 0.f};

  for (int cich = 0; cich < 16; ++cich) {
    __syncthreads();
    for (int u = tid; u < 4 * 66 * 4; u += 512) {
      int o = u & 3; int t2 = u >> 2;
      int xp = t2 % 66; int row = t2 / 66;
      int gy = y2 - 1 + row, gx = xp - 1;
      short8 v = {0, 0, 0, 0, 0, 0, 0, 0};
      if ((unsigned)gy < 64u && (unsigned)gx < 64u)
        v = *(const short8*)&hin[((size_t)((b * 64 + gy) * 64 + gx)) * 512 + (cich << 5) + (o << 3)];
      #pragma unroll
      for (int i = 0; i < 8; ++i) if (v[i] < 0) v[i] = 0;   // relu(h)
      *(short8*)&s_in[(row * 66 + xp) * XS + (o << 3)] = v;
    }
    __syncthreads();

    #pragma unroll
    for (int kk = 0; kk < 9; ++kk) {
      int ky = kk / 3, kx = kk - ky * 3;
      short8 af[2];
      #pragma unroll
      for (int f = 0; f < 2; ++f) {
        int cg = wq_ * 2 + f;
        af[f] = *(const short8*)&w1q[(((size_t)(cg * 9 + kk) * 16 + cich) * 64 + lane) * 8];
      }
      #pragma unroll
      for (int p = 0; p < 4; ++p) {
        short8 bv = *(const short8*)&s_in[((wr + ky) * 66 + p * 16 + m + kx) * XS + (quad << 3)];
        #pragma unroll
        for (int f = 0; f < 2; ++f)
          acc[f][p] = __builtin_amdgcn_mfma_f32_16x16x32_bf16(af[f], bv, acc[f][p], 0, 0, 0);
      }
    }
  }

  // write t (bias + relu) to LDS in [px][ch] layout
  __syncthreads();
  #pragma unroll
  for (int f = 0; f < 2; ++f) {
    int co4 = wq_ * 32 + f * 16 + quad * 4;
    floatx4 b4 = *(const floatx4*)&b1[co4];
    #pragma unroll
    for (int p = 0; p < 4; ++p) {
      int pxg = wr * 64 + p * 16 + m;
      short4v sv;
      #pragma unroll
      for (int r = 0; r < 4; ++r) {
        float v = acc[f][p][r] + b4[r];
        sv[r] = f2bf(v > 0.f ? v : 0.f);
      }
      *(short4v*)&t_tile[pxg * TS + co4] = sv;
    }
  }
  __syncthreads();

  // ---- 1x1: out = h + W2 * t (+ optional relu) ----
  // wave handles row wr, out-co range [wq_*128, wq_*128+128)
  floatx4 acc2[8][4];
  #pragma unroll
  for (int f = 0; f < 8; ++f)
    #pragma unroll
    for (int p = 0; p < 4; ++p) acc2[f][p] = (floatx4){0.f, 0.f, 0.f, 0.f};

  #pragma unroll
  for (int cich = 0; cich < 4; ++cich) {
    short8 bv2[4];
    #pragma unroll
    for (int p = 0; p < 4; ++p)
      bv2[p] = *(const short8*)&t_tile[(wr * 64 + p * 16 + m) * TS + (cich << 5) + (quad << 3)];
    #pragma unroll
    for (int f = 0; f < 8; ++f) {
      int cg2 = wq_ * 8 + f;
      short8 af2 = *(const short8*)&w2q[(((size_t)cg2 * 4 + cich) * 64 + lane) * 8];
      #pragma unroll
      for (int p = 0; p < 4; ++p)
        acc2[f][p] = __builtin_amdgcn_mfma_f32_16x16x32_bf16(af2, bv2[p], acc2[f][p], 0, 0, 0);
    }
  }

  int pixrow = (b * 64 + y2 + wr) * 64;
  #pragma unroll
  for (int f = 0; f < 8; ++f) {
    int co4 = wq_ * 128 + f * 16 + quad * 4;
    floatx4 b4 = *(const floatx4*)&b2[co4];
    #pragma unroll
    for (int p = 0; p < 4; ++p) {
      int x = p * 16 + m;
      size_t oidx = (size_t)(pixrow + x) * 512 + co4;
      short4v rr = *(const short4v*)&hin[oidx];
      short4v sv;
      #pragma unroll
      for (int r = 0; r < 4; ++r) {
        float v = acc2[f][p][r] + b4[r] + bf2f(rr[r]);
        if (relu_out) v = v > 0.f ? v : 0.f;
        sv[r] = f2bf(v);
      }
      *(short4v*)&hout[oidx] = sv;
    }
  }
}

// ---------------- MFMA vector quantizer ----------------
__global__ __launch_bounds__(128) void k_vqm(
    const short* __restrict__ z, const short* __restrict__ cbq,
    const float* __restrict__ cb, const float* __restrict__ cc,
    short* __restrict__ zq, float* __restrict__ vq_sum)
{
  __shared__ __align__(16) short zl[64 * 264];
  __shared__ float ccl[1024];
  __shared__ int widx[64];
  __shared__ float red[128];

  int tid = threadIdx.x;
  int lane = tid & 63, wave = tid >> 6;
  int m = lane & 15, quad = lane >> 4;
  size_t px0 = (size_t)blockIdx.x * 64;

  for (int u = tid; u < 64 * 32; u += 128) {
    int px = u >> 5, o = u & 31;
    *(short8*)&zl[px * 264 + o * 8] = *(const short8*)&z[(px0 + px) * 256 + o * 8];
  }
  for (int u = tid; u < 1024; u += 128) ccl[u] = cc[u];
  __syncthreads();

  short8 bf[2][8];
  #pragma unroll
  for (int f = 0; f < 2; ++f) {
    int px = wave * 32 + f * 16 + m;
    #pragma unroll
    for (int kc = 0; kc < 8; ++kc)
      bf[f][kc] = *(const short8*)&zl[px * 264 + kc * 32 + quad * 8];
  }

  float best[2] = {3.4e38f, 3.4e38f};
  int bid[2] = {0, 0};

  for (int cg = 0; cg < 64; ++cg) {
    floatx4 acc0 = (floatx4){0.f, 0.f, 0.f, 0.f};
    floatx4 acc1 = (floatx4){0.f, 0.f, 0.f, 0.f};
    #pragma unroll
    for (int kc = 0; kc < 8; ++kc) {
      short8 af = *(const short8*)&cbq[((size_t)(cg * 8 + kc) * 64 + lane) * 8];
      acc0 = __builtin_amdgcn_mfma_f32_16x16x32_bf16(af, bf[0][kc], acc0, 0, 0, 0);
      acc1 = __builtin_amdgcn_mfma_f32_16x16x32_bf16(af, bf[1][kc], acc1, 0, 0, 0);
    }
    floatx4 c4 = *(const floatx4*)&ccl[cg * 16 + quad * 4];
    #pragma unroll
    for (int r = 0; r < 4; ++r) {
      int code = cg * 16 + quad * 4 + r;
      float s0 = c4[r] - 2.f * acc0[r];
      float s1 = c4[r] - 2.f * acc1[r];
      if (s0 < best[0]) { best[0] = s0; bid[0] = code; }
      if (s1 < best[1]) { best[1] = s1; bid[1] = code; }
    }
  }

  #pragma unroll
  for (int f = 0; f < 2; ++f) {
    float s = best[f]; int i = bid[f];
    #pragma unroll
    for (int off = 16; off <= 32; off <<= 1) {
      float s2 = __shfl_xor(s, off);
      int i2 = __shfl_xor(i, off);
      if (s2 < s || (s2 == s && i2 < i)) { s = s2; i = i2; }
    }
    if (quad == 0) widx[wave * 32 + f * 16 + m] = i;
  }
  __syncthreads();

  float local = 0.f;
  for (int px = 0; px < 64; ++px) {
    int code = widx[px];
    #pragma unroll
    for (int k = 0; k < 2; ++k) {
      int d = tid + k * 128;
      float q = cb[(size_t)code * 256 + d];
      float zv = bf2f(zl[px * 264 + d]);
      float df = q - zv;
      local += df * df;
      zq[(px0 + px) * 256 + d] = f2bf(q);
    }
  }
  red[tid] = local;
  __syncthreads();
  for (int off = 64; off > 0; off >>= 1) {
    if (tid < off) red[tid] += red[tid + off];
    __syncthreads();
  }
  if (tid == 0) atomicAdd(vq_sum, red[0]);
}

// ---------------- deconv 256->3, k4 s2 p1 (NHWC bf16 in, NCHW fp32 out) ----
__global__ __launch_bounds__(256) void k_deconv(
    const short* __restrict__ h, const short* __restrict__ wdt,
    const float* __restrict__ bias, const float* __restrict__ x,
    float* __restrict__ xr, float* __restrict__ recon_sum)
{
  __shared__ float red[256];
  int idx = blockIdx.x * 256 + threadIdx.x;
  int xc = idx & 127;
  int yc = (idx >> 7) & 127;
  int b = idx >> 14;

  int vy[2], vky[2], nvy = 0;
  int ky0 = (yc + 1) & 1;
  #pragma unroll
  for (int t = 0; t < 2; ++t) {
    int ky = ky0 + 2 * t;
    int iy = (yc + 1 - ky) >> 1;
    if (iy >= 0 && iy < 64) { vky[nvy] = ky; vy[nvy] = iy; ++nvy; }
  }
  int vx[2], vkx[2], nvx = 0;
  int kx0 = (xc + 1) & 1;
  #pragma unroll
  for (int t = 0; t < 2; ++t) {
    int kx = kx0 + 2 * t;
    int ix = (xc + 1 - kx) >> 1;
    if (ix >= 0 && ix < 64) { vkx[nvx] = kx; vx[nvx] = ix; ++nvx; }
  }

  float acc[3] = {bias[0], bias[1], bias[2]};
  for (int ty = 0; ty < nvy; ++ty)
    for (int tx = 0; tx < nvx; ++tx) {
      int kk = vky[ty] * 4 + vkx[tx];
      const short* hp = h + ((size_t)((b * 64 + vy[ty]) * 64 + vx[tx])) * 256;
      const short* wp = wdt + kk * 768;
      for (int c = 0; c < 256; c += 8) {
        short8 hv = *(const short8*)&hp[c];
        short8 w0 = *(const short8*)&wp[c];
        short8 w1 = *(const short8*)&wp[256 + c];
        short8 w2 = *(const short8*)&wp[512 + c];
        #pragma unroll
        for (int i = 0; i < 8; ++i) {
          float hf = bf2f(hv[i]);
          acc[0] += hf * bf2f(w0[i]);
          acc[1] += hf * bf2f(w1[i]);
          acc[2] += hf * bf2f(w2[i]);
        }
      }
    }

  float local = 0.f;
  #pragma unroll
  for (int o = 0; o < 3; ++o) {
    size_t oi = ((size_t)(b * 3 + o) * 128 + yc) * 128 + xc;
    xr[oi] = acc[o];
    float df = acc[o] - x[oi];
    local += df * df;
  }
  red[threadIdx.x] = local;
  __syncthreads();
  for (int off = 128; off > 0; off >>= 1) {
    if (threadIdx.x < off) red[threadIdx.x] += red[threadIdx.x + off];
    __syncthreads();
  }
  if (threadIdx.x == 0) atomicAdd(recon_sum, red[0]);
}

// ---------------- finalize ----------------
__global__ void k_finalize(const float* __restrict__ a, float* __restrict__ out)
{
  float e = a[0] * (1.f / (32768.f * 256.f));
  float recon = a[1] * (1.f / 393216.f);
  out[393216] = recon + 1.25f * e;
  out[393217] = recon;
}

// ---------------------------------------------------------------------------
extern "C" void kernel_launch(void* const* d_in, const int* in_sizes, int n_in,
                              void* d_out, int out_size, void* d_ws, size_t ws_size,
                              hipStream_t stream)
{
  const float* x    = (const float*)d_in[0];
  const float* ec0w = (const float*)d_in[1];
  const float* ec0b = (const float*)d_in[2];
  const float* bn0g = (const float*)d_in[3];
  const float* bn0b = (const float*)d_in[4];
  const float* ec1w = (const float*)d_in[5];
  const float* ec1b = (const float*)d_in[6];
  const float* bn1g = (const float*)d_in[7];
  const float* bn1b = (const float*)d_in[8];
  const float* ec2w = (const float*)d_in[9];
  const float* ec2b = (const float*)d_in[10];
  const float* erw1 = (const float*)d_in[11];
  const float* erb1 = (const float*)d_in[12];
  const float* erw2 = (const float*)d_in[13];
  const float* erb2 = (const float*)d_in[14];
  const float* ec3w = (const float*)d_in[15];
  const float* ec3b = (const float*)d_in[16];
  const float* cb   = (const float*)d_in[17];
  const float* dc0w = (const float*)d_in[18];
  const float* dc0b = (const float*)d_in[19];
  const float* drw1 = (const float*)d_in[20];
  const float* drb1 = (const float*)d_in[21];
  const float* drw2 = (const float*)d_in[22];
  const float* drb2 = (const float*)d_in[23];
  const float* dc1w = (const float*)d_in[24];
  const float* dc1b = (const float*)d_in[25];
  const float* ddw  = (const float*)d_in[26];
  const float* ddb  = (const float*)d_in[27];

  short* wsu = (short*)d_ws;
  short* wq_ec1 = wsu;                       // 1,179,648
  short* wq_ec2 = wsu + 1179648;             // 2,359,296
  short* wq_ec3 = wsu + 3538944;             // 1,179,648
  short* wq_dc0 = wsu + 4718592;             // 1,179,648
  short* wq_dc1 = wsu + 5898240;             // 1,179,648
  short* wq_er1 = wsu + 7077888;             // 16 x 589,824
  short* wq_er2 = wsu + 16515072;            // 16 x 65,536
  short* wq_dr1 = wsu + 17563648;            // 16 x 589,824
  short* wq_dr2 = wsu + 27000832;            // 16 x 65,536
  short* wq_dd  = wsu + 28049408;            // 12,288
  short* cbq    = wsu + 28061696;            // 262,144
  short* wq0    = wsu + 28323840;            // 16,384 (conv0 A-frags, K pad 64)
  short* im2c   = wsu + 28340224;            // 2,097,152 ([32768][64])
  short* bufA   = wsu + 30437376;            // 16,777,216 (NHWC, C<=512)
  short* bufB   = wsu + 47214592;            // 16,777,216
  short* bufZ   = wsu + 63991808;            //  8,388,608 (C=256)
  float* stats  = (float*)(wsu + 80769024);
  float* bn0_sums = stats;                   // 512
  float* bn1_sums = stats + 512;             // 1024
  float* accums   = stats + 1536;            // 2
  float* bn0_ss   = stats + 1664;            // 512
  float* bn1_ss   = stats + 2176;            // 1024
  float* ccn      = stats + 3200;            // 1024

  k_init<<<1, 256, 0, stream>>>(stats);

  // ---- weight swizzles ----
  k_wswz0m<<<64, 256, 0, stream>>>(ec0w, wq0);
  k_wswz_dd<<<48, 256, 0, stream>>>(ddw, wq_dd);
  k_ccn<<<4, 256, 0, stream>>>(cb, ccn);
  k_wswz<<<1024, 256, 0, stream>>>(cb, cbq, 256, 1, 262144);
  k_wswz<<<4608, 256, 0, stream>>>(ec1w, wq_ec1, 256, 9, 1179648);
  k_wswz<<<9216, 256, 0, stream>>>(ec2w, wq_ec2, 512, 9, 2359296);
  k_wswz<<<4608, 256, 0, stream>>>(ec3w, wq_ec3, 512, 9, 1179648);
  k_wswz<<<4608, 256, 0, stream>>>(dc0w, wq_dc0, 256, 9, 1179648);
  k_wswz<<<4608, 256, 0, stream>>>(dc1w, wq_dc1, 512, 9, 1179648);
  k_wswz<<<dim3(2304, 16), 256, 0, stream>>>(erw1, wq_er1, 512, 9, 589824);
  k_wswz<<<dim3(256, 16), 256, 0, stream>>>(erw2, wq_er2, 128, 1, 65536);
  k_wswz<<<dim3(2304, 16), 256, 0, stream>>>(drw1, wq_dr1, 512, 9, 589824);
  k_wswz<<<dim3(256, 16), 256, 0, stream>>>(drw2, wq_dr2, 128, 1, 65536);

  // ---- encoder ----
  k_im2col<<<8192, 256, 0, stream>>>(x, im2c);
  k_mconv<1><<<dim3(2, 32, 8), 256, 0, stream>>>(im2c, bufA, nullptr, bn0_sums,
                                                 wq0, ec0b, 64, 256, F_STATS);
  k_bnfin<<<1, 512, 0, stream>>>(bn0_sums, bn0g, bn0b, bn0_ss, 256);
  k_mconv<3><<<dim3(4, 32, 8), 256, 0, stream>>>(bufA, bufB, bn0_ss, bn1_sums,
                                                 wq_ec1, ec1b, 256, 512,
                                                 F_IN_BNORM | F_STATS);
  k_bnfin<<<1, 512, 0, stream>>>(bn1_sums, bn1g, bn1b, bn1_ss, 512);
  k_mconv<3><<<dim3(4, 32, 8), 256, 0, stream>>>(bufB, bufA, bn1_ss, nullptr,
                                                 wq_ec2, ec2b, 512, 512, F_IN_BNORM);

  {
    short* cur = bufA; short* alt = bufB;
    for (int l = 0; l < 16; ++l) {
      k_res<<<dim3(32, 8), 512, 0, stream>>>(cur, alt,
                                             wq_er1 + (size_t)l * 589824, erb1 + l * 128,
                                             wq_er2 + (size_t)l * 65536, erb2 + l * 512,
                                             ((l & 3) == 3) ? 1 : 0);
      short* tmp = cur; cur = alt; alt = tmp;
    }
  }
  // 16 swaps -> ends back in bufA
  k_mconv<3><<<dim3(2, 32, 8), 256, 0, stream>>>(bufA, bufZ, nullptr, nullptr,
                                                 wq_ec3, ec3b, 512, 256, 0);

  // ---- VQ ---- (zq -> bufB)
  k_vqm<<<512, 128, 0, stream>>>(bufZ, cbq, cb, ccn, bufB, accums + 0);

  // ---- decoder ----
  k_mconv<3><<<dim3(4, 32, 8), 256, 0, stream>>>(bufB, bufA, nullptr, nullptr,
                                                 wq_dc0, dc0b, 256, 512, 0);
  {
    short* cur = bufA; short* alt = bufB;
    for (int l = 0; l < 16; ++l) {
      k_res<<<dim3(32, 8), 512, 0, stream>>>(cur, alt,
                                             wq_dr1 + (size_t)l * 589824, drb1 + l * 128,
                                             wq_dr2 + (size_t)l * 65536, drb2 + l * 512,
                                             ((l & 3) == 3) ? 1 : 0);
      short* tmp = cur; cur = alt; alt = tmp;
    }
  }
  k_mconv<3><<<dim3(2, 32, 8), 256, 0, stream>>>(bufA, bufB, nullptr, nullptr,
                                                 wq_dc1, dc1b, 512, 256, F_OUT_RELU);

  // ---- deconv + losses ----
  k_deconv<<<512, 256, 0, stream>>>(bufB, wq_dd, ddb, x, (float*)d_out, accums + 1);
  k_finalize<<<1, 1, 0, stream>>>(accums, (float*)d_out);
}